// Round 10
// baseline (138.109 us; speedup 1.0000x reference)
//
#include <hip/hip_runtime.h>

// SDConv via MFMA: out[b,o,h,w] = sum_{c,tap} weight[o,c,tap] * t[c,tap]
//   t = rsqrt(1 + (V[nb]-V[c])^2) * (U[nb]-U[c]), zero-padded neighborhoods,
//   center tap contributes 0 -> K = 16 ch * 8 taps = 128.
// v_mfma_f32_16x16x32_f16 mapping (A and B share the same (lane-group, elem)
// -> (c,tap) rule, so the HW k-permutation cancels):
//   A[16 px][32 k]: lane computes t for pixel (lane&15), channel 4*kc+(lane>>4)
//   B[32 k][16 o] : lane holds weights for o=(lane&15), channel 4*kc+(lane>>4)
//   D: o=lane&15, px=(lane>>4)*4+reg  [m89-verified]
// Round-7: XCD-bijective block swizzle (one batch image per XCD -> halo
// refetch becomes same-L2 hit) + ROWS=4 (6.1 waves/SIMD for TLP) while
// keeping the 4-kc interleaved load chains for ILP.

constexpr int Bn = 8, Ci = 16, Co = 16, H = 224, W = 224;
constexpr int HW = H * W;
constexpr int ROWS = 4;                    // pixel rows per wave
constexpr int TILES_X = W / 16;            // 14
constexpr int TILES_Y = H / (2 * ROWS);    // 28 (block = 2 waves stacked)
constexpr int TILES_PER_BATCH = TILES_X * TILES_Y;  // 392 == NWG/8 exactly

typedef _Float16 f16x8 __attribute__((ext_vector_type(8)));
typedef float    f32x4 __attribute__((ext_vector_type(4)));

// Load {w-1, w, w+1} of row h. Interior: constant-offset loads.
template <bool EDGE>
__device__ __forceinline__ void load_row(const float* __restrict__ plane,
                                         int h, int w, float* __restrict__ r) {
  if (!EDGE) {
    const float* q = plane + h * W + w;
    r[0] = q[-1]; r[1] = q[0]; r[2] = q[1];
  } else {
    if ((unsigned)h < (unsigned)H) {       // wave-uniform branch
      const float* q = plane + h * W + w;
      r[0] = (w >= 1)     ? q[-1] : 0.0f;  // per-lane exec-masked
      r[1] = q[0];
      r[2] = (w + 1 < W) ? q[1] : 0.0f;
    } else {
      r[0] = 0.0f; r[1] = 0.0f; r[2] = 0.0f;
    }
  }
}

template <bool EDGE>
__device__ __forceinline__ void sdconv_wave(
    const float* __restrict__ U, const float* __restrict__ V,
    const float* __restrict__ Wg, float* __restrict__ Out,
    int b, int h0, int w0, int lane) {
  const int px = lane & 15;   // pixel (w) index in tile; also o for B/D
  const int cg = lane >> 4;   // channel sub-group 0..3
  const int w  = w0 + px;

  // ---- B fragments (weights), built once ----
  f16x8 bfrag[4];
#pragma unroll
  for (int kc = 0; kc < 4; ++kc) {
    const int c = 4 * kc + cg;
    const float* wp = Wg + (px * Ci + c) * 9;   // px plays the role of o
#pragma unroll
    for (int j = 0; j < 8; ++j) {
      const int tap = (j < 4) ? j : j + 1;      // skip center tap
      bfrag[kc][j] = (_Float16)wp[tap];
    }
  }

  f32x4 d[ROWS];
#pragma unroll
  for (int r = 0; r < ROWS; ++r) d[r] = (f32x4){0.f, 0.f, 0.f, 0.f};

  const float* up[4];
  const float* vp[4];
#pragma unroll
  for (int kc = 0; kc < 4; ++kc) {
    const int c = 4 * kc + cg;
    up[kc] = U + ((size_t)(b * Ci + c)) * HW;
    vp[kc] = V + ((size_t)(b * Ci + c)) * HW;
  }

  // rolling 3-row windows per kc, mod-3 slots (all indices compile-time)
  float u[4][3][3], v[4][3][3];
#pragma unroll
  for (int kc = 0; kc < 4; ++kc) {
    load_row<EDGE>(up[kc], h0 - 1, w, u[kc][0]);
    load_row<EDGE>(vp[kc], h0 - 1, w, v[kc][0]);
    load_row<EDGE>(up[kc], h0,     w, u[kc][1]);
    load_row<EDGE>(vp[kc], h0,     w, v[kc][1]);
  }

#pragma unroll
  for (int r = 0; r < ROWS; ++r) {
    const int st = r % 3;         // top    = row h0+r-1
    const int sm = (r + 1) % 3;   // mid    = row h0+r
    const int sb = (r + 2) % 3;   // bottom = row h0+r+1 (loaded now)

    // issue ALL loads of this row-step first: 4 independent chains in flight
#pragma unroll
    for (int kc = 0; kc < 4; ++kc) {
      load_row<EDGE>(up[kc], h0 + r + 1, w, u[kc][sb]);
      load_row<EDGE>(vp[kc], h0 + r + 1, w, v[kc][sb]);
    }

#pragma unroll
    for (int kc = 0; kc < 4; ++kc) {
      const float uc = u[kc][sm][1], vc = v[kc][sm][1];
      const int slot[3] = {st, sm, sb};
      f16x8 a;
      int j = 0;
#pragma unroll
      for (int dh = 0; dh < 3; ++dh) {
#pragma unroll
        for (int dw = 0; dw < 3; ++dw) {
          if (dh == 1 && dw == 1) continue;
          const float vd = v[kc][slot[dh]][dw] - vc;
          const float s  = __builtin_amdgcn_rsqf(fmaf(vd, vd, 1.0f)); // LAMBDA=1
          a[j++] = (_Float16)(s * (u[kc][slot[dh]][dw] - uc));
        }
      }
      d[r] = __builtin_amdgcn_mfma_f32_16x16x32_f16(a, bfrag[kc], d[r], 0, 0, 0);
    }
  }

  // ---- store: lane holds D[px=4*cg+r'][o=px-index], 4 consecutive w ----
  const int wst = w0 + 4 * cg;    // 16B-aligned (w0 % 16 == 0)
  const int o   = px;
#pragma unroll
  for (int r = 0; r < ROWS; ++r) {
    float* op = Out + (((size_t)b * Co + o) * H + (h0 + r)) * W + wst;
    *reinterpret_cast<f32x4*>(op) = d[r];
  }
}

__global__ __launch_bounds__(128, 4)
void sdconv_mfma(const float* __restrict__ U, const float* __restrict__ V,
                 const float* __restrict__ Wg, float* __restrict__ Out) {
  // XCD-bijective swizzle: NWG = 3136, 3136/8 = 392 = tiles per batch image.
  // HW round-robins blockIdx across XCDs -> bz = hw&7 puts one full batch
  // image on each XCD; rem = hw>>3 walks that image in row-major tile order,
  // so all halo-sharing neighbor tiles live in the same 4 MB L2.
  const int hw  = blockIdx.x;
  const int bz  = hw & 7;          // batch  (== XCD id)
  const int rem = hw >> 3;         // 0..391 within the batch image
  const int by  = rem / TILES_X;
  const int bx  = rem - by * TILES_X;

  const int lane = threadIdx.x & 63;
  const int wv   = threadIdx.x >> 6;            // 0..1
  const int w0 = bx * 16;
  const int h0 = by * (2 * ROWS) + wv * ROWS;   // wave's first pixel row

  const bool edge = (bx == 0) | (bx == TILES_X - 1) |
                    (by == 0) | (by == TILES_Y - 1);
  if (edge)
    sdconv_wave<true >(U, V, Wg, Out, bz, h0, w0, lane);
  else
    sdconv_wave<false>(U, V, Wg, Out, bz, h0, w0, lane);
}

extern "C" void kernel_launch(void* const* d_in, const int* in_sizes, int n_in,
                              void* d_out, int out_size, void* d_ws, size_t ws_size,
                              hipStream_t stream) {
  const float* U  = (const float*)d_in[0];
  const float* V  = (const float*)d_in[1];
  const float* Wg = (const float*)d_in[2];
  float* Out = (float*)d_out;

  dim3 grid(TILES_X * TILES_Y * Bn);  // 3136 blocks, 1D for the swizzle
  dim3 block(128);                    // 2 waves; each wave: 16w x 4h pixels
  sdconv_mfma<<<grid, block, 0, stream>>>(U, V, Wg, Out);
}

// Round 12
// 112.300 us; speedup vs baseline: 1.2298x; 1.2298x over previous
//
#include <hip/hip_runtime.h>

// SDConv via MFMA: out[b,o,h,w] = sum_{c,tap} weight[o,c,tap] * t[c,tap]
//   t = rsqrt(1 + (V[nb]-V[c])^2) * (U[nb]-U[c]), zero-padded neighborhoods,
//   center tap contributes 0 -> K = 16 ch * 8 taps = 128.
// v_mfma_f32_16x16x32_f16 mapping (A and B share the same (lane-group, elem)
// -> (c,tap) rule, so the HW k-permutation cancels):
//   A[16 px][32 k]: lane computes t for pixel (lane&15), channel 4*kc+(lane>>4)
//   B[32 k][16 o] : lane holds weights for o=(lane&15), channel 4*kc+(lane>>4)
//   D: o=lane&15, px=(lane>>4)*4+reg  [m89-verified]
// Round-7: XCD-bijective block swizzle (one batch image per XCD -> halo
// refetch becomes same-L2 hit) + ROWS=4 + 4-kc interleaved load chains.
// Round-11: launch_bounds(128,2) -- the (128,4) cap forced 64 VGPRs and
// spilled ~25 MB/dispatch to scratch (WRITE_SIZE doubled, dur regressed).
// Natural VGPR use (~110) already permits 4 waves/SIMD without spills.

constexpr int Bn = 8, Ci = 16, Co = 16, H = 224, W = 224;
constexpr int HW = H * W;
constexpr int ROWS = 4;                    // pixel rows per wave
constexpr int TILES_X = W / 16;            // 14
constexpr int TILES_Y = H / (2 * ROWS);    // 28 (block = 2 waves stacked)
constexpr int TILES_PER_BATCH = TILES_X * TILES_Y;  // 392 == NWG/8 exactly

typedef _Float16 f16x8 __attribute__((ext_vector_type(8)));
typedef float    f32x4 __attribute__((ext_vector_type(4)));

// Load {w-1, w, w+1} of row h. Interior: constant-offset loads.
template <bool EDGE>
__device__ __forceinline__ void load_row(const float* __restrict__ plane,
                                         int h, int w, float* __restrict__ r) {
  if (!EDGE) {
    const float* q = plane + h * W + w;
    r[0] = q[-1]; r[1] = q[0]; r[2] = q[1];
  } else {
    if ((unsigned)h < (unsigned)H) {       // wave-uniform branch
      const float* q = plane + h * W + w;
      r[0] = (w >= 1)     ? q[-1] : 0.0f;  // per-lane exec-masked
      r[1] = q[0];
      r[2] = (w + 1 < W) ? q[1] : 0.0f;
    } else {
      r[0] = 0.0f; r[1] = 0.0f; r[2] = 0.0f;
    }
  }
}

template <bool EDGE>
__device__ __forceinline__ void sdconv_wave(
    const float* __restrict__ U, const float* __restrict__ V,
    const float* __restrict__ Wg, float* __restrict__ Out,
    int b, int h0, int w0, int lane) {
  const int px = lane & 15;   // pixel (w) index in tile; also o for B/D
  const int cg = lane >> 4;   // channel sub-group 0..3
  const int w  = w0 + px;

  // ---- B fragments (weights), built once ----
  f16x8 bfrag[4];
#pragma unroll
  for (int kc = 0; kc < 4; ++kc) {
    const int c = 4 * kc + cg;
    const float* wp = Wg + (px * Ci + c) * 9;   // px plays the role of o
#pragma unroll
    for (int j = 0; j < 8; ++j) {
      const int tap = (j < 4) ? j : j + 1;      // skip center tap
      bfrag[kc][j] = (_Float16)wp[tap];
    }
  }

  f32x4 d[ROWS];
#pragma unroll
  for (int r = 0; r < ROWS; ++r) d[r] = (f32x4){0.f, 0.f, 0.f, 0.f};

  const float* up[4];
  const float* vp[4];
#pragma unroll
  for (int kc = 0; kc < 4; ++kc) {
    const int c = 4 * kc + cg;
    up[kc] = U + ((size_t)(b * Ci + c)) * HW;
    vp[kc] = V + ((size_t)(b * Ci + c)) * HW;
  }

  // rolling 3-row windows per kc, mod-3 slots (all indices compile-time)
  float u[4][3][3], v[4][3][3];
#pragma unroll
  for (int kc = 0; kc < 4; ++kc) {
    load_row<EDGE>(up[kc], h0 - 1, w, u[kc][0]);
    load_row<EDGE>(vp[kc], h0 - 1, w, v[kc][0]);
    load_row<EDGE>(up[kc], h0,     w, u[kc][1]);
    load_row<EDGE>(vp[kc], h0,     w, v[kc][1]);
  }

#pragma unroll
  for (int r = 0; r < ROWS; ++r) {
    const int st = r % 3;         // top    = row h0+r-1
    const int sm = (r + 1) % 3;   // mid    = row h0+r
    const int sb = (r + 2) % 3;   // bottom = row h0+r+1 (loaded now)

    // issue ALL loads of this row-step first: 4 independent chains in flight
#pragma unroll
    for (int kc = 0; kc < 4; ++kc) {
      load_row<EDGE>(up[kc], h0 + r + 1, w, u[kc][sb]);
      load_row<EDGE>(vp[kc], h0 + r + 1, w, v[kc][sb]);
    }

#pragma unroll
    for (int kc = 0; kc < 4; ++kc) {
      const float uc = u[kc][sm][1], vc = v[kc][sm][1];
      const int slot[3] = {st, sm, sb};
      f16x8 a;
      int j = 0;
#pragma unroll
      for (int dh = 0; dh < 3; ++dh) {
#pragma unroll
        for (int dw = 0; dw < 3; ++dw) {
          if (dh == 1 && dw == 1) continue;
          const float vd = v[kc][slot[dh]][dw] - vc;
          const float s  = __builtin_amdgcn_rsqf(fmaf(vd, vd, 1.0f)); // LAMBDA=1
          a[j++] = (_Float16)(s * (u[kc][slot[dh]][dw] - uc));
        }
      }
      d[r] = __builtin_amdgcn_mfma_f32_16x16x32_f16(a, bfrag[kc], d[r], 0, 0, 0);
    }
  }

  // ---- store: lane holds D[px=4*cg+r'][o=px-index], 4 consecutive w ----
  const int wst = w0 + 4 * cg;    // 16B-aligned (w0 % 16 == 0)
  const int o   = px;
#pragma unroll
  for (int r = 0; r < ROWS; ++r) {
    float* op = Out + (((size_t)b * Co + o) * H + (h0 + r)) * W + wst;
    *reinterpret_cast<f32x4*>(op) = d[r];
  }
}

__global__ __launch_bounds__(128, 2)
void sdconv_mfma(const float* __restrict__ U, const float* __restrict__ V,
                 const float* __restrict__ Wg, float* __restrict__ Out) {
  // XCD-bijective swizzle: NWG = 3136, 3136/8 = 392 = tiles per batch image.
  // HW round-robins blockIdx across XCDs -> bz = hw&7 puts one full batch
  // image on each XCD; rem = hw>>3 walks that image in row-major tile order,
  // so all halo-sharing neighbor tiles live in the same 4 MB L2.
  const int hw  = blockIdx.x;
  const int bz  = hw & 7;          // batch  (== XCD id)
  const int rem = hw >> 3;         // 0..391 within the batch image
  const int by  = rem / TILES_X;
  const int bx  = rem - by * TILES_X;

  const int lane = threadIdx.x & 63;
  const int wv   = threadIdx.x >> 6;            // 0..1
  const int w0 = bx * 16;
  const int h0 = by * (2 * ROWS) + wv * ROWS;   // wave's first pixel row

  const bool edge = (bx == 0) | (bx == TILES_X - 1) |
                    (by == 0) | (by == TILES_Y - 1);
  if (edge)
    sdconv_wave<true >(U, V, Wg, Out, bz, h0, w0, lane);
  else
    sdconv_wave<false>(U, V, Wg, Out, bz, h0, w0, lane);
}

extern "C" void kernel_launch(void* const* d_in, const int* in_sizes, int n_in,
                              void* d_out, int out_size, void* d_ws, size_t ws_size,
                              hipStream_t stream) {
  const float* U  = (const float*)d_in[0];
  const float* V  = (const float*)d_in[1];
  const float* Wg = (const float*)d_in[2];
  float* Out = (float*)d_out;

  dim3 grid(TILES_X * TILES_Y * Bn);  // 3136 blocks, 1D for the swizzle
  dim3 block(128);                    // 2 waves; each wave: 16w x 4h pixels
  sdconv_mfma<<<grid, block, 0, stream>>>(U, V, Wg, Out);
}